// Round 8
// baseline (57.401 us; speedup 1.0000x reference)
//
#include <hip/hip_runtime.h>

namespace {

typedef float v4f __attribute__((ext_vector_type(4)));

struct M3 { float a[9]; };
struct V3 { float x, y, z; };

__device__ __forceinline__ V3 mulv_add(const M3& R, V3 o, V3 p) {
    V3 r;
    r.x = fmaf(R.a[0], o.x, fmaf(R.a[1], o.y, fmaf(R.a[2], o.z, p.x)));
    r.y = fmaf(R.a[3], o.x, fmaf(R.a[4], o.y, fmaf(R.a[5], o.z, p.y)));
    r.z = fmaf(R.a[6], o.x, fmaf(R.a[7], o.y, fmaf(R.a[8], o.z, p.z)));
    return r;
}

__device__ __forceinline__ M3 mulm(const M3& R, const M3& A) {
    M3 D;
#pragma unroll
    for (int i = 0; i < 3; ++i) {
#pragma unroll
        for (int k = 0; k < 3; ++k) {
            D.a[i*3+k] = fmaf(R.a[i*3+0], A.a[0*3+k],
                         fmaf(R.a[i*3+1], A.a[1*3+k],
                              R.a[i*3+2] * A.a[2*3+k]));
        }
    }
    return D;
}

template <int REL>
__device__ __forceinline__ float getf(const float4* s) {
    constexpr int Q = REL >> 2;
    constexpr int C = REL & 3;
    if constexpr (C == 0) return s[Q].x;
    else if constexpr (C == 1) return s[Q].y;
    else if constexpr (C == 2) return s[Q].z;
    else return s[Q].w;
}

template <int J, int BASE>
__device__ __forceinline__ M3 loadA(const float4* s) {
    constexpr int K = 9 * J - BASE;
    M3 A;
    A.a[0] = getf<K+0>(s); A.a[1] = getf<K+1>(s); A.a[2] = getf<K+2>(s);
    A.a[3] = getf<K+3>(s); A.a[4] = getf<K+4>(s); A.a[5] = getf<K+5>(s);
    A.a[6] = getf<K+6>(s); A.a[7] = getf<K+7>(s); A.a[8] = getf<K+8>(s);
    return A;
}

__device__ __forceinline__ V3 loadOff(const float* __restrict__ off, int j) {
    V3 o; o.x = off[3*j+0]; o.y = off[3*j+1]; o.z = off[3*j+2]; return o;
}

// async global->LDS, 16B per lane; dst is the WAVE-UNIFORM base (HW adds lane*16)
__device__ __forceinline__ void gload16(const float4* src, float4* lds_base) {
    __builtin_amdgcn_global_load_lds(
        (const __attribute__((address_space(1))) void*)src,
        (__attribute__((address_space(3))) void*)lds_base, 16, 0, 0);
}

// 42 vmem ops total per call: 7 + 14 reg loads, 21 global_load_lds
__device__ __forceinline__ void issue_loads(const float4* gc, int l,
                                            float4* buf,
                                            float4 (&s2)[7], float4 (&s3)[14]) {
    const float4* row = gc + (size_t)l * 54;
#pragma unroll
    for (int c = 0; c < 7; ++c) s2[c] = row[27 + c];     // A_12..A_14
#pragma unroll
    for (int c = 0; c < 14; ++c) s3[c] = row[36 + c];    // A_16..A_21
#pragma unroll
    for (int k = 0; k < 21; ++k) {                       // A_1..A_9 coalesced
        int p = k * 64 + l;
        int s = p / 21, j = p - s * 21;                  // magic-mul div
        gload16(gc + s * 54 + 2 + j, buf + k * 64);
    }
}

#define OBP(J, P) do { ob[3*(J)+0] = (P).x; ob[3*(J)+1] = (P).y; ob[3*(J)+2] = (P).z; } while (0)

// full tree walk for one chunk; stage reuses `buf` (consumed-first, race-free)
__device__ __forceinline__ void compute_store(
    int l, float4* buf, const float4 (&s2)[7], const float4 (&s3)[14],
    const float* __restrict__ off, v4f* oc) {

    float4 s1[21];
    {
        const float4* r1 = buf + l * 21;   // quad-stride 5 (odd): conflict-free
#pragma unroll
        for (int c = 0; c < 21; ++c) s1[c] = r1[c];
    }
    constexpr int B1 = 8, B2 = 108, B3 = 144;

    float ob[72];
    ob[0] = 0.f; ob[1] = 0.f; ob[2] = 0.f;               // root position

    V3 p1 = loadOff(off, 1), p2 = loadOff(off, 2), p3 = loadOff(off, 3);
    OBP(1, p1); OBP(2, p2); OBP(3, p3);
    M3 R1 = loadA<1, B1>(s1);
    M3 R2 = loadA<2, B1>(s1);
    M3 R3 = loadA<3, B1>(s1);

    V3 p4 = mulv_add(R1, loadOff(off, 4), p1);  M3 R4 = mulm(R1, loadA<4, B1>(s1));  OBP(4, p4);
    V3 p5 = mulv_add(R2, loadOff(off, 5), p2);  M3 R5 = mulm(R2, loadA<5, B1>(s1));  OBP(5, p5);
    V3 p6 = mulv_add(R3, loadOff(off, 6), p3);  M3 R6 = mulm(R3, loadA<6, B1>(s1));  OBP(6, p6);
    V3 p7 = mulv_add(R4, loadOff(off, 7), p4);  M3 R7 = mulm(R4, loadA<7, B1>(s1));  OBP(7, p7);
    V3 p8 = mulv_add(R5, loadOff(off, 8), p5);  M3 R8 = mulm(R5, loadA<8, B1>(s1));  OBP(8, p8);
    V3 p9 = mulv_add(R6, loadOff(off, 9), p6);  M3 R9 = mulm(R6, loadA<9, B1>(s1));  OBP(9, p9);

    V3 p10 = mulv_add(R7, loadOff(off, 10), p7);  OBP(10, p10);   // leaf
    V3 p11 = mulv_add(R8, loadOff(off, 11), p8);  OBP(11, p11);   // leaf

    V3 p12 = mulv_add(R9, loadOff(off, 12), p9);  M3 R12 = mulm(R9, loadA<12, B2>(s2));  OBP(12, p12);
    V3 p13 = mulv_add(R9, loadOff(off, 13), p9);  M3 R13 = mulm(R9, loadA<13, B2>(s2));  OBP(13, p13);
    V3 p14 = mulv_add(R9, loadOff(off, 14), p9);  M3 R14 = mulm(R9, loadA<14, B2>(s2));  OBP(14, p14);
    V3 p15 = mulv_add(R12, loadOff(off, 15), p12);  OBP(15, p15); // head leaf

    V3 p16 = mulv_add(R13, loadOff(off, 16), p13);  M3 R16 = mulm(R13, loadA<16, B3>(s3));  OBP(16, p16);
    V3 p17 = mulv_add(R14, loadOff(off, 17), p14);  M3 R17 = mulm(R14, loadA<17, B3>(s3));  OBP(17, p17);
    V3 p18 = mulv_add(R16, loadOff(off, 18), p16);  M3 R18 = mulm(R16, loadA<18, B3>(s3));  OBP(18, p18);
    V3 p19 = mulv_add(R17, loadOff(off, 19), p17);  M3 R19 = mulm(R17, loadA<19, B3>(s3));  OBP(19, p19);
    V3 p20 = mulv_add(R18, loadOff(off, 20), p18);  M3 R20 = mulm(R18, loadA<20, B3>(s3));  OBP(20, p20);
    V3 p21 = mulv_add(R19, loadOff(off, 21), p19);  M3 R21 = mulm(R19, loadA<21, B3>(s3));  OBP(21, p21);

    V3 p22 = mulv_add(R20, loadOff(off, 22), p20);  OBP(22, p22); // hand leaf
    V3 p23 = mulv_add(R21, loadOff(off, 23), p21);  OBP(23, p23); // hand leaf

    // ---- transpose via this (already-consumed) buffer as [18][65] stage ----
    float4* stage = buf;
    asm volatile("" ::: "memory");
#pragma unroll
    for (int r = 0; r < 18; ++r) {
        float4 v;
        v.x = ob[4*r+0]; v.y = ob[4*r+1]; v.z = ob[4*r+2]; v.w = ob[4*r+3];
        stage[r * 65 + l] = v;                  // quad (r+l)%8: uniform, free
    }

    // ---- coalesced nontemporal output (18 stores -> vmcnt) ----
#pragma unroll
    for (int i = 0; i < 18; ++i) {
        int e4 = i * 64 + l;
        int s  = e4 / 18;                       // magic-mul div
        int r  = e4 - s * 18;
        float4 v = stage[r * 65 + s];
        v4f vv; vv.x = v.x; vv.y = v.y; vv.z = v.z; vv.w = v.w;
        __builtin_nontemporal_store(vv, &oc[e4]);
    }
}

// 1 wave/block, 8 chunks of 64 samples per block; LDS 43 KB; grid=512 (2/CU)
__global__ __launch_bounds__(64, 1)
void fk_kernel(const float* __restrict__ ja, const float* __restrict__ off,
               float* __restrict__ out) {
    __shared__ __align__(16) float4 lds[2688];   // 2 x [64][21] f4 = 43,008 B
    float4* buf0 = lds;
    float4* buf1 = lds + 1344;

    const int l = threadIdx.x;                   // 0..63
    const int b = blockIdx.x;
    const float4* ja4 = reinterpret_cast<const float4*>(ja);
    v4f* o4 = reinterpret_cast<v4f*>(out);

    auto gc = [&](int c) { return ja4 + (size_t)(b * 8 + c) * 3456; };  // 64*54
    auto oc = [&](int c) { return o4  + (size_t)(b * 8 + c) * 1152; };  // 64*18

    float4 s2A[7], s3A[14], s2B[7], s3B[14];

    // prologue: chunk 0 in flight (42 ops outstanding)
    issue_loads(gc(0), l, buf0, s2A, s3A);

#pragma unroll 1
    for (int it = 0; it < 4; ++it) {
        const int c0 = 2 * it, c1 = 2 * it + 1;

        // prefetch odd chunk, then counted wait: drains [stores(c1-1), loads(c0)],
        // leaves loads(c1) = 42 in flight under compute(c0)
        issue_loads(gc(c1), l, buf1, s2B, s3B);
        asm volatile("s_waitcnt vmcnt(42)" ::: "memory");
        compute_store(l, buf0, s2A, s3A, off, oc(c0));

        if (it < 3) {
            // prefetch next even chunk; wait drains [stores(c0), loads(c1)]
            issue_loads(gc(c0 + 2), l, buf0, s2A, s3A);
            asm volatile("s_waitcnt vmcnt(42)" ::: "memory");
        } else {
            asm volatile("s_waitcnt vmcnt(0)" ::: "memory");  // final drain
        }
        compute_store(l, buf1, s2B, s3B, off, oc(c1));
    }
}

}  // namespace

extern "C" void kernel_launch(void* const* d_in, const int* in_sizes, int n_in,
                              void* d_out, int out_size, void* d_ws, size_t ws_size,
                              hipStream_t stream) {
    const float* ja  = (const float*)d_in[0];
    const float* off = (const float*)d_in[1];
    float* out = (float*)d_out;

    int N = in_sizes[0] / 216;     // 262144
    int grid = N / 512;            // 512 blocks x 8 chunks x 64 samples
    hipLaunchKernelGGL(fk_kernel, dim3(grid), dim3(64), 0, stream, ja, off, out);
}